// Round 5
// baseline (1385.625 us; speedup 1.0000x reference)
//
#include <hip/hip_runtime.h>
#include <stdint.h>

// Problem: B=32, N=512, E=1024, H=8, L=3, FF=2048, KD=128, DK=16
// Transport dtype (f32 vs bf16) detected on device; compute bf16 MFMA + f32 master h.

typedef __attribute__((ext_vector_type(8))) short short8;
typedef __attribute__((ext_vector_type(4))) float floatx4;

#define NORM_ 0.08838834764831845f   // 1/sqrt(128)

__device__ __forceinline__ float bf2f(unsigned short u) {
    union { unsigned int i; float f; } x; x.i = ((unsigned int)u) << 16; return x.f;
}
__device__ __forceinline__ unsigned short f2bf(float f) {  // RNE
    union { float f; unsigned int i; } x; x.f = f;
    unsigned int u = x.i;
    u += 0x7FFFu + ((u >> 16) & 1u);
    return (unsigned short)(u >> 16);
}
__device__ __forceinline__ void async_cp16(const void* g, void* l) {
    __builtin_amdgcn_global_load_lds((const __attribute__((address_space(1))) void*)g,
                                     (__attribute__((address_space(3))) void*)l, 16, 0, 0);
}

// ---- transport dtype detection -------------------------------------------
__global__ __launch_bounds__(256) void detect_dtype(const unsigned int* __restrict__ x,
                                                    int* __restrict__ flag)
{
    __shared__ int good, bad;
    if (threadIdx.x == 0) { good = 0; bad = 0; }
    __syncthreads();
    int g = 0, b = 0;
    for (int i = threadIdx.x; i < 4096; i += 256) {
        unsigned int lo = x[i] & 0xFFFFu;
        if (lo != 0u) {
            unsigned int e = (lo >> 7) & 0xFFu;
            if (e >= 90u && e <= 145u) ++g; else ++b;
        }
    }
    atomicAdd(&good, g); atomicAdd(&bad, b);
    __syncthreads();
    if (threadIdx.x == 0) *flag = (bad > good) ? 1 : 0;   // 1 = f32 transport
}

__global__ __launch_bounds__(256) void conv_to_bf16(const void* __restrict__ src,
                                                    unsigned short* __restrict__ dst,
                                                    int n, const int* __restrict__ flag)
{
    const int i = (blockIdx.x * 256 + threadIdx.x) * 8;
    if (i >= n) return;
    if (*flag) {
        const float* s = (const float*)src + i;
        floatx4 a = *(const floatx4*)s;
        floatx4 b = *(const floatx4*)(s + 4);
        short8 o;
        o[0] = (short)f2bf(a[0]); o[1] = (short)f2bf(a[1]);
        o[2] = (short)f2bf(a[2]); o[3] = (short)f2bf(a[3]);
        o[4] = (short)f2bf(b[0]); o[5] = (short)f2bf(b[1]);
        o[6] = (short)f2bf(b[2]); o[7] = (short)f2bf(b[3]);
        *(short8*)(dst + i) = o;
    } else {
        *(short8*)(dst + i) = *(const short8*)((const unsigned short*)src + i);
    }
}

__global__ __launch_bounds__(256) void init_h(const void* __restrict__ x,
                                              float* __restrict__ hf,
                                              unsigned short* __restrict__ hb,
                                              const int* __restrict__ flag)
{
    const size_t i = ((size_t)blockIdx.x * 256 + threadIdx.x) * 8;
    if (*flag) {
        const float* s = (const float*)x + i;
        floatx4 a = *(const floatx4*)s;
        floatx4 b = *(const floatx4*)(s + 4);
        short8 o;
        o[0] = (short)f2bf(a[0]); o[1] = (short)f2bf(a[1]);
        o[2] = (short)f2bf(a[2]); o[3] = (short)f2bf(a[3]);
        o[4] = (short)f2bf(b[0]); o[5] = (short)f2bf(b[1]);
        o[6] = (short)f2bf(b[2]); o[7] = (short)f2bf(b[3]);
        *(short8*)(hb + i) = o;
        *(floatx4*)(hf + i) = a;
        *(floatx4*)(hf + i + 4) = b;
    } else {
        short8 v = *(const short8*)((const unsigned short*)x + i);
        *(short8*)(hb + i) = v;
        #pragma unroll
        for (int e = 0; e < 8; ++e) hf[i + e] = bf2f((unsigned short)v[e]);
    }
}

__global__ __launch_bounds__(256) void mask_expand(const unsigned int* __restrict__ mraw,
                                                   float* __restrict__ maskf)
{
    __shared__ unsigned int r[4];
    if (threadIdx.x < 4) r[threadIdx.x] = 0;
    __syncthreads();
    unsigned int gt1 = 0, badb = 0, badh = 0, lo3f = 0;
    for (int i = threadIdx.x; i < 4096; i += 256) {
        unsigned int w = mraw[i];
        if (w > 1u) gt1 = 1;
        if (w & 0xFEFEFEFEu) badb = 1;
        unsigned int lo = w & 0xFFFFu, hi = w >> 16;
        if ((lo != 0u && lo != 0x3F80u) || (hi != 0u && hi != 0x3F80u)) badh = 1;
        if (lo == 0x3F80u) lo3f = 1;
    }
    if (gt1) atomicOr(&r[0], 1u);
    if (badb) atomicOr(&r[1], 1u);
    if (badh) atomicOr(&r[2], 1u);
    if (lo3f) atomicOr(&r[3], 1u);
    __syncthreads();
    int cls;
    if (!r[0]) cls = 0;
    else if (!r[1]) cls = 1;
    else if (!r[2]) cls = r[3] ? 2 : 3;
    else cls = 0;

    const int gid = blockIdx.x * 256 + threadIdx.x;
    bool m;
    if (cls == 0)      m = ((const int*)mraw)[gid] != 0;
    else if (cls == 1) m = ((const unsigned char*)mraw)[gid] != 0;
    else if (cls == 2) m = ((const unsigned short*)mraw)[gid] != 0;
    else               m = mraw[gid] != 0u;
    maskf[gid] = m ? 1.0f : 0.0f;
}

enum { EPI_NONE = 0, EPI_BIAS_RELU = 1, EPI_BIAS_RES = 2 };

// C[m,n] = sum_k A[m,k]*B[n,k]. 128x128 tile, templated BK, async global_load_lds x16.
// Grid: x = bn (fastest; consecutive blocks share the A-slab -> L2 reuse), y = bm, z = qkv.
template<int EPI, int BK>
__global__ __launch_bounds__(256) void gemm_bt(
    const unsigned short* __restrict__ A,
    const unsigned short* __restrict__ Bq,
    const unsigned short* __restrict__ Bk,
    const unsigned short* __restrict__ Bv,
    unsigned short* __restrict__ Cq,
    unsigned short* __restrict__ Ck,
    unsigned short* __restrict__ Cv,
    const unsigned short* __restrict__ bias,
    float* __restrict__ hf,
    unsigned short* __restrict__ hb,
    int N, int K)
{
    __shared__ __align__(16) unsigned short As[128 * BK];
    __shared__ __align__(16) unsigned short Bs[128 * BK];

    const int t = threadIdx.x;
    const int lane = t & 63;
    const int wave = t >> 6;
    const int bn = blockIdx.x;
    const int bm = blockIdx.y;
    const int bz = blockIdx.z;

    const unsigned short* Bmat = (bz == 0) ? Bq : ((bz == 1) ? Bk : Bv);
    unsigned short* C = (bz == 0) ? Cq : ((bz == 1) ? Ck : Cv);

    const int wm = (wave >> 1) * 64;
    const int wn = (wave & 1) * 64;

    // staging: 16B chunks, linear chunk id == t within each 256-chunk round.
    constexpr int CPR  = BK / 8;     // chunks per row
    constexpr int ROWS = 2048 / BK;  // rows per round (256 chunks)
    constexpr int RNDS = BK / 16;    // rounds per matrix (128 rows total)
    const int srow = t / CPR;
    const int scol = (t % CPR) * 8;
    const unsigned short* Ag = A + (size_t)(bm * 128 + srow) * K + scol;
    const unsigned short* Bg = Bmat + (size_t)(bn * 128 + srow) * K + scol;
    unsigned short* Asd = &As[t * 8];
    unsigned short* Bsd = &Bs[t * 8];
    const size_t gstep = (size_t)ROWS * K;   // global row step per round

    const int fl = lane & 15;
    const int fk = (lane >> 4) * 8;
    int aoff[4], boff[4];
    #pragma unroll
    for (int i = 0; i < 4; ++i) {
        aoff[i] = (wm + i * 16 + fl) * BK + fk;
        boff[i] = (wn + i * 16 + fl) * BK + fk;
    }

    floatx4 acc[4][4];
    #pragma unroll
    for (int i = 0; i < 4; ++i)
        #pragma unroll
        for (int j = 0; j < 4; ++j) {
            acc[i][j][0] = 0.f; acc[i][j][1] = 0.f;
            acc[i][j][2] = 0.f; acc[i][j][3] = 0.f;
        }

    for (int k0 = 0; k0 < K; k0 += BK) {
        __syncthreads();
        #pragma unroll
        for (int r = 0; r < RNDS; ++r) {
            async_cp16(Ag + k0 + r * gstep, Asd + r * 2048);
            async_cp16(Bg + k0 + r * gstep, Bsd + r * 2048);
        }
        __syncthreads();

        #pragma unroll
        for (int ks = 0; ks < BK; ks += 32) {
            short8 af[4], bfr[4];
            #pragma unroll
            for (int i = 0; i < 4; ++i) af[i] = *(const short8*)&As[aoff[i] + ks];
            #pragma unroll
            for (int j = 0; j < 4; ++j) bfr[j] = *(const short8*)&Bs[boff[j] + ks];
            #pragma unroll
            for (int i = 0; i < 4; ++i)
                #pragma unroll
                for (int j = 0; j < 4; ++j)
                    acc[i][j] = __builtin_amdgcn_mfma_f32_16x16x32_bf16(af[i], bfr[j], acc[i][j], 0, 0, 0);
        }
    }

    const int r0 = (lane >> 4) * 4;
    #pragma unroll
    for (int j = 0; j < 4; ++j) {
        const int gcol = bn * 128 + wn + j * 16 + fl;
        float bval = 0.f;
        if (EPI != EPI_NONE) bval = bf2f(bias[gcol]);
        #pragma unroll
        for (int i = 0; i < 4; ++i) {
            const int growb = bm * 128 + wm + i * 16 + r0;
            #pragma unroll
            for (int r = 0; r < 4; ++r) {
                const size_t idx = (size_t)(growb + r) * N + gcol;
                float v = acc[i][j][r];
                if (EPI == EPI_NONE) {
                    C[idx] = f2bf(v);
                } else if (EPI == EPI_BIAS_RELU) {
                    v += bval;
                    v = v > 0.f ? v : 0.f;
                    C[idx] = f2bf(v);
                } else {
                    float nh = hf[idx] + v + bval;
                    hf[idx] = nh;
                    hb[idx] = f2bf(nh);
                }
            }
        }
    }
}

// MFMA flash attention (validated round 4). blockIdx = pair*4 + qquarter.
__global__ __launch_bounds__(128) void attn_mfma(
    const unsigned short* __restrict__ Q,
    const unsigned short* __restrict__ Kx,
    const unsigned short* __restrict__ Vx,
    const float* __restrict__ maskf,
    unsigned short* __restrict__ Out)
{
    __shared__ __align__(16) unsigned short Vt[16 * 520];
    __shared__ __align__(16) unsigned short Pb[2][64 * 40];
    __shared__ float Ms[512];
    __shared__ float cnt_s;

    const int t = threadIdx.x;
    const int lane = t & 63;
    const int wave = t >> 6;
    const int p = blockIdx.x >> 2;
    const int qq = blockIdx.x & 3;
    const int b2 = p & 31;
    const int h2 = p >> 5;
    const int fm = lane & 15;
    const int g = lane >> 4;

    const unsigned short* Qg = Q + (size_t)p * 8192;
    const unsigned short* Kg = Kx + (size_t)p * 8192;
    const unsigned short* Vg = Vx + (size_t)p * 8192;

    #pragma unroll
    for (int rr = 0; rr < 4; ++rr) {
        const int row = t * 4 + rr;
        short8 v0 = *(const short8*)&Vg[row * 16];
        short8 v1 = *(const short8*)&Vg[row * 16 + 8];
        #pragma unroll
        for (int d = 0; d < 8; ++d) Vt[d * 520 + row] = (unsigned short)v0[d];
        #pragma unroll
        for (int d = 0; d < 8; ++d) Vt[(d + 8) * 520 + row] = (unsigned short)v1[d];
    }
    if (t == 0) cnt_s = 0.f;
    __syncthreads();
    float pc = 0.f;
    #pragma unroll
    for (int it = 0; it < 4; ++it) {
        int i = it * 128 + t;
        float mv = maskf[b2 * 512 + i];
        Ms[i] = mv; pc += mv;
    }
    atomicAdd(&cnt_s, pc);
    __syncthreads();
    const float cnt = cnt_s;

    const int qbase = qq * 128 + wave * 64;
    short8 qf[4];
    #pragma unroll
    for (int i = 0; i < 4; ++i) {
        short8 z = {0,0,0,0,0,0,0,0};
        if (g < 2) z = *(const short8*)&Qg[(qbase + i * 16 + fm) * 16 + g * 8];
        qf[i] = z;
    }

    float m_[4][4], l_[4][4];
    floatx4 O[4];
    #pragma unroll
    for (int i = 0; i < 4; ++i) {
        #pragma unroll
        for (int r = 0; r < 4; ++r) { m_[i][r] = -1e30f; l_[i][r] = 0.f; }
        O[i][0] = 0.f; O[i][1] = 0.f; O[i][2] = 0.f; O[i][3] = 0.f;
    }

    unsigned short* Pw = &Pb[wave][0];

    for (int kb = 0; kb < 512; kb += 32) {
        short8 kf0 = {0,0,0,0,0,0,0,0}, kf1 = {0,0,0,0,0,0,0,0};
        if (g < 2) {
            kf0 = *(const short8*)&Kg[(kb + fm) * 16 + g * 8];
            kf1 = *(const short8*)&Kg[(kb + 16 + fm) * 16 + g * 8];
        }
        const float msk0 = Ms[kb + fm];
        const float msk1 = Ms[kb + 16 + fm];

        floatx4 zero4 = {0.f, 0.f, 0.f, 0.f};
        floatx4 s0[4], s1[4];
        #pragma unroll
        for (int i = 0; i < 4; ++i) {
            s0[i] = __builtin_amdgcn_mfma_f32_16x16x32_bf16(qf[i], kf0, zero4, 0, 0, 0);
            s1[i] = __builtin_amdgcn_mfma_f32_16x16x32_bf16(qf[i], kf1, zero4, 0, 0, 0);
        }

        #pragma unroll
        for (int i = 0; i < 4; ++i) {
            #pragma unroll
            for (int r = 0; r < 4; ++r) {
                float a0 = (msk0 != 0.f) ? -1e30f : s0[i][r] * NORM_;
                float a1 = (msk1 != 0.f) ? -1e30f : s1[i][r] * NORM_;
                float mx = fmaxf(a0, a1);
                mx = fmaxf(mx, __shfl_xor(mx, 1));
                mx = fmaxf(mx, __shfl_xor(mx, 2));
                mx = fmaxf(mx, __shfl_xor(mx, 4));
                mx = fmaxf(mx, __shfl_xor(mx, 8));
                const float mo = m_[i][r];
                const float mn = fmaxf(mo, mx);
                const float alpha = __expf(mo - mn);
                float w0 = (msk0 != 0.f) ? 0.f : __expf(a0 - mn);
                float w1 = (msk1 != 0.f) ? 0.f : __expf(a1 - mn);
                float rs = w0 + w1;
                rs += __shfl_xor(rs, 1);
                rs += __shfl_xor(rs, 2);
                rs += __shfl_xor(rs, 4);
                rs += __shfl_xor(rs, 8);
                l_[i][r] = l_[i][r] * alpha + rs;
                m_[i][r] = mn;
                O[i][r] *= alpha;
                const int qloc = i * 16 + g * 4 + r;
                Pw[qloc * 40 + fm] = f2bf(w0);
                Pw[qloc * 40 + 16 + fm] = f2bf(w1);
            }
        }
        asm volatile("s_waitcnt lgkmcnt(0)" ::: "memory");

        short8 vtf = *(const short8*)&Vt[fm * 520 + kb + g * 8];
        #pragma unroll
        for (int i = 0; i < 4; ++i) {
            short8 pf = *(const short8*)&Pw[(i * 16 + fm) * 40 + g * 8];
            O[i] = __builtin_amdgcn_mfma_f32_16x16x32_bf16(pf, vtf, O[i], 0, 0, 0);
        }
    }

    #pragma unroll
    for (int i = 0; i < 4; ++i) {
        #pragma unroll
        for (int r = 0; r < 4; ++r) {
            const float M = fmaxf(m_[i][r], -30.f);
            const float adj = __expf(m_[i][r] - M);
            const float lf = l_[i][r] * adj + cnt * __expf(-30.f - M);
            const float oval = O[i][r] * adj / lf;
            const int n = qbase + i * 16 + g * 4 + r;
            Out[((size_t)(b2 * 512 + n)) * 128 + h2 * 16 + fm] = f2bf(oval);
        }
    }
}

__global__ __launch_bounds__(256) void write_h(const float* __restrict__ hf,
                                               void* __restrict__ out,
                                               const int* __restrict__ flag)
{
    const size_t i = ((size_t)blockIdx.x * 256 + threadIdx.x) * 4;
    floatx4 v = *(const floatx4*)&hf[i];
    if (*flag) {
        *(floatx4*)((float*)out + i) = v;
    } else {
        unsigned int p0 = (unsigned int)f2bf(v[0]) | ((unsigned int)f2bf(v[1]) << 16);
        unsigned int p1 = (unsigned int)f2bf(v[2]) | ((unsigned int)f2bf(v[3]) << 16);
        unsigned int* o = (unsigned int*)((unsigned short*)out + i);
        o[0] = p0; o[1] = p1;
    }
}

__global__ __launch_bounds__(256) void mean_kernel(const float* __restrict__ hf,
                                                   void* __restrict__ out,
                                                   const int* __restrict__ flag)
{
    const int b = blockIdx.x >> 2;
    const int e = ((blockIdx.x & 3) * 256) + threadIdx.x;
    float s = 0.f;
    for (int n = 0; n < 512; ++n) s += hf[((size_t)(b * 512 + n)) * 1024 + e];
    s *= (1.0f / 512.0f);
    const size_t off = (size_t)16384 * 1024 + b * 1024 + e;
    if (*flag) ((float*)out)[off] = s;
    else       ((unsigned short*)out)[off] = f2bf(s);
}

extern "C" void kernel_launch(void* const* d_in, const int* in_sizes, int n_in,
                              void* d_out, int out_size, void* d_ws, size_t ws_size,
                              hipStream_t stream)
{
    const void* x  = d_in[0];
    const unsigned int* mask = (const unsigned int*)d_in[1];

    char* ws = (char*)d_ws;
    float* hf = (float*)ws;                     ws += (size_t)16384 * 1024 * 4;   // 64 MB
    unsigned short* hb = (unsigned short*)ws;   ws += (size_t)16384 * 1024 * 2;   // 32 MB
    char* shared_rg = ws;                       ws += (size_t)16384 * 2048 * 2;   // 64 MB
    unsigned short* act = (unsigned short*)shared_rg;
    unsigned short* q  = (unsigned short*)shared_rg;
    unsigned short* k  = q + (size_t)16384 * 128;
    unsigned short* v  = k + (size_t)16384 * 128;
    unsigned short* ao = v + (size_t)16384 * 128;
    unsigned short* cWq = (unsigned short*)ws;  ws += (size_t)393216 * 2;
    unsigned short* cWk = (unsigned short*)ws;  ws += (size_t)393216 * 2;
    unsigned short* cWv = (unsigned short*)ws;  ws += (size_t)393216 * 2;
    unsigned short* cWo = (unsigned short*)ws;  ws += (size_t)393216 * 2;
    unsigned short* cbo = (unsigned short*)ws;  ws += (size_t)3072 * 2;
    unsigned short* cW1 = (unsigned short*)ws;  ws += (size_t)6291456 * 2;
    unsigned short* cb1 = (unsigned short*)ws;  ws += (size_t)6144 * 2;
    unsigned short* cW2 = (unsigned short*)ws;  ws += (size_t)6291456 * 2;
    unsigned short* cb2 = (unsigned short*)ws;  ws += (size_t)3072 * 2;
    float* maskf = (float*)ws;                  ws += (size_t)16384 * 4;
    int* flag = (int*)ws;                       ws += 256;

    detect_dtype<<<1, 256, 0, stream>>>((const unsigned int*)x, flag);

    auto conv = [&](const void* s, unsigned short* d, int n) {
        conv_to_bf16<<<(n / 8 + 255) / 256, 256, 0, stream>>>(s, d, n, flag);
    };
    conv(d_in[2], cWq, 393216);
    conv(d_in[3], cWk, 393216);
    conv(d_in[4], cWv, 393216);
    conv(d_in[5], cWo, 393216);
    conv(d_in[6], cbo, 3072);
    conv(d_in[7], cW1, 6291456);
    conv(d_in[8], cb1, 6144);
    conv(d_in[9], cW2, 6291456);
    conv(d_in[10], cb2, 3072);

    mask_expand<<<64, 256, 0, stream>>>(mask, maskf);
    init_h<<<8192, 256, 0, stream>>>(x, hf, hb, flag);

    for (int l = 0; l < 3; ++l) {
        const unsigned short* wq  = cWq + (size_t)l * 131072;
        const unsigned short* wk  = cWk + (size_t)l * 131072;
        const unsigned short* wv  = cWv + (size_t)l * 131072;
        const unsigned short* wo  = cWo + (size_t)l * 131072;
        const unsigned short* bol = cbo + (size_t)l * 1024;
        const unsigned short* w1  = cW1 + (size_t)l * 2097152;
        const unsigned short* b1l = cb1 + (size_t)l * 2048;
        const unsigned short* w2  = cW2 + (size_t)l * 2097152;
        const unsigned short* b2l = cb2 + (size_t)l * 1024;

        // grid: x = bn (fastest -> A-slab L2 reuse), y = bm
        gemm_bt<EPI_NONE, 64><<<dim3(1, 128, 3), 256, 0, stream>>>(
            hb, wq, wk, wv, q, k, v, nullptr, nullptr, nullptr, 128, 1024);
        attn_mfma<<<1024, 128, 0, stream>>>(q, k, v, maskf, ao);
        gemm_bt<EPI_BIAS_RES, 64><<<dim3(8, 128, 1), 256, 0, stream>>>(
            ao, wo, wo, wo, nullptr, nullptr, nullptr, bol, hf, hb, 1024, 128);
        gemm_bt<EPI_BIAS_RELU, 64><<<dim3(16, 128, 1), 256, 0, stream>>>(
            hb, w1, w1, w1, act, act, act, b1l, nullptr, nullptr, 2048, 1024);
        gemm_bt<EPI_BIAS_RES, 64><<<dim3(8, 128, 1), 256, 0, stream>>>(
            act, w2, w2, w2, nullptr, nullptr, nullptr, b2l, hf, hb, 1024, 2048);
    }

    write_h<<<16384, 256, 0, stream>>>(hf, d_out, flag);
    mean_kernel<<<128, 256, 0, stream>>>(hf, d_out, flag);
}

// Round 6
// 1236.874 us; speedup vs baseline: 1.1203x; 1.1203x over previous
//
#include <hip/hip_runtime.h>
#include <stdint.h>

// Problem: B=32, N=512, E=1024, H=8, L=3, FF=2048, KD=128, DK=16
// Transport dtype (f32 vs bf16) detected on device; compute bf16 MFMA + f32 master h.

typedef __attribute__((ext_vector_type(8))) short short8;
typedef __attribute__((ext_vector_type(4))) float floatx4;

#define NORM_ 0.08838834764831845f   // 1/sqrt(128)

__device__ __forceinline__ float bf2f(unsigned short u) {
    union { unsigned int i; float f; } x; x.i = ((unsigned int)u) << 16; return x.f;
}
__device__ __forceinline__ unsigned short f2bf(float f) {  // RNE
    union { float f; unsigned int i; } x; x.f = f;
    unsigned int u = x.i;
    u += 0x7FFFu + ((u >> 16) & 1u);
    return (unsigned short)(u >> 16);
}
__device__ __forceinline__ void async_cp16(const void* g, void* l) {
    __builtin_amdgcn_global_load_lds((const __attribute__((address_space(1))) void*)g,
                                     (__attribute__((address_space(3))) void*)l, 16, 0, 0);
}

// ---- transport dtype detection -------------------------------------------
__global__ __launch_bounds__(256) void detect_dtype(const unsigned int* __restrict__ x,
                                                    int* __restrict__ flag)
{
    __shared__ int good, bad;
    if (threadIdx.x == 0) { good = 0; bad = 0; }
    __syncthreads();
    int g = 0, b = 0;
    for (int i = threadIdx.x; i < 4096; i += 256) {
        unsigned int lo = x[i] & 0xFFFFu;
        if (lo != 0u) {
            unsigned int e = (lo >> 7) & 0xFFu;
            if (e >= 90u && e <= 145u) ++g; else ++b;
        }
    }
    atomicAdd(&good, g); atomicAdd(&bad, b);
    __syncthreads();
    if (threadIdx.x == 0) *flag = (bad > good) ? 1 : 0;   // 1 = f32 transport
}

__global__ __launch_bounds__(256) void conv_to_bf16(const void* __restrict__ src,
                                                    unsigned short* __restrict__ dst,
                                                    int n, const int* __restrict__ flag)
{
    const int i = (blockIdx.x * 256 + threadIdx.x) * 8;
    if (i >= n) return;
    if (*flag) {
        const float* s = (const float*)src + i;
        floatx4 a = *(const floatx4*)s;
        floatx4 b = *(const floatx4*)(s + 4);
        short8 o;
        o[0] = (short)f2bf(a[0]); o[1] = (short)f2bf(a[1]);
        o[2] = (short)f2bf(a[2]); o[3] = (short)f2bf(a[3]);
        o[4] = (short)f2bf(b[0]); o[5] = (short)f2bf(b[1]);
        o[6] = (short)f2bf(b[2]); o[7] = (short)f2bf(b[3]);
        *(short8*)(dst + i) = o;
    } else {
        *(short8*)(dst + i) = *(const short8*)((const unsigned short*)src + i);
    }
}

__global__ __launch_bounds__(256) void init_h(const void* __restrict__ x,
                                              float* __restrict__ hf,
                                              unsigned short* __restrict__ hb,
                                              const int* __restrict__ flag)
{
    const size_t i = ((size_t)blockIdx.x * 256 + threadIdx.x) * 8;
    if (*flag) {
        const float* s = (const float*)x + i;
        floatx4 a = *(const floatx4*)s;
        floatx4 b = *(const floatx4*)(s + 4);
        short8 o;
        o[0] = (short)f2bf(a[0]); o[1] = (short)f2bf(a[1]);
        o[2] = (short)f2bf(a[2]); o[3] = (short)f2bf(a[3]);
        o[4] = (short)f2bf(b[0]); o[5] = (short)f2bf(b[1]);
        o[6] = (short)f2bf(b[2]); o[7] = (short)f2bf(b[3]);
        *(short8*)(hb + i) = o;
        *(floatx4*)(hf + i) = a;
        *(floatx4*)(hf + i + 4) = b;
    } else {
        short8 v = *(const short8*)((const unsigned short*)x + i);
        *(short8*)(hb + i) = v;
        #pragma unroll
        for (int e = 0; e < 8; ++e) hf[i + e] = bf2f((unsigned short)v[e]);
    }
}

__global__ __launch_bounds__(256) void mask_expand(const unsigned int* __restrict__ mraw,
                                                   float* __restrict__ maskf)
{
    __shared__ unsigned int r[4];
    if (threadIdx.x < 4) r[threadIdx.x] = 0;
    __syncthreads();
    unsigned int gt1 = 0, badb = 0, badh = 0, lo3f = 0;
    for (int i = threadIdx.x; i < 4096; i += 256) {
        unsigned int w = mraw[i];
        if (w > 1u) gt1 = 1;
        if (w & 0xFEFEFEFEu) badb = 1;
        unsigned int lo = w & 0xFFFFu, hi = w >> 16;
        if ((lo != 0u && lo != 0x3F80u) || (hi != 0u && hi != 0x3F80u)) badh = 1;
        if (lo == 0x3F80u) lo3f = 1;
    }
    if (gt1) atomicOr(&r[0], 1u);
    if (badb) atomicOr(&r[1], 1u);
    if (badh) atomicOr(&r[2], 1u);
    if (lo3f) atomicOr(&r[3], 1u);
    __syncthreads();
    int cls;
    if (!r[0]) cls = 0;
    else if (!r[1]) cls = 1;
    else if (!r[2]) cls = r[3] ? 2 : 3;
    else cls = 0;

    const int gid = blockIdx.x * 256 + threadIdx.x;
    bool m;
    if (cls == 0)      m = ((const int*)mraw)[gid] != 0;
    else if (cls == 1) m = ((const unsigned char*)mraw)[gid] != 0;
    else if (cls == 2) m = ((const unsigned short*)mraw)[gid] != 0;
    else               m = mraw[gid] != 0u;
    maskf[gid] = m ? 1.0f : 0.0f;
}

enum { EPI_NONE = 0, EPI_BIAS_RELU = 1, EPI_BIAS_RES = 2 };

// C[m,n] = sum_k A[m,k]*B[n,k]. 128x128 tile, BK=64, DOUBLE-buffered LDS with
// fine-grained vmcnt (next tile's global_load_lds stay in flight across the
// barrier), XOR-swizzled LDS chunks (kills ds_read_b128 bank conflicts).
// Grid: x = bm (fastest; consecutive blocks share B-slab), y = bn, z = qkv.
template<int EPI>
__global__ __launch_bounds__(256) void gemm_bt(
    const unsigned short* __restrict__ A,
    const unsigned short* __restrict__ Bq,
    const unsigned short* __restrict__ Bk,
    const unsigned short* __restrict__ Bv,
    unsigned short* __restrict__ Cq,
    unsigned short* __restrict__ Ck,
    unsigned short* __restrict__ Cv,
    const unsigned short* __restrict__ bias,
    float* __restrict__ hf,
    unsigned short* __restrict__ hb,
    int N, int K)
{
    constexpr int BK = 64;
    __shared__ __align__(16) unsigned short As[2][128 * BK];   // 2 x 16 KB
    __shared__ __align__(16) unsigned short Bs[2][128 * BK];   // 2 x 16 KB

    const int t = threadIdx.x;
    const int lane = t & 63;
    const int wave = t >> 6;
    const int bm = blockIdx.x;
    const int bn = blockIdx.y;
    const int bz = blockIdx.z;

    const unsigned short* Bmat = (bz == 0) ? Bq : ((bz == 1) ? Bk : Bv);
    unsigned short* C = (bz == 0) ? Cq : ((bz == 1) ? Ck : Cv);

    const int wm = (wave >> 1) * 64;
    const int wn = (wave & 1) * 64;

    // staging: LDS chunk p = t + r*256 (16B each) holds global chunk
    // (row = t/8 + r*32, kc = (t&7) ^ ((t/8)&7))  -- XOR swizzle.
    const int srow = t >> 3;                               // 0..31
    const int scol = (((t & 7) ^ ((t >> 3) & 7)) * 8);     // swizzled source col
    const unsigned short* Ag = A + (size_t)(bm * 128 + srow) * K + scol;
    const unsigned short* Bg = Bmat + (size_t)(bn * 128 + srow) * K + scol;
    const size_t gstep = (size_t)32 * K;                   // 32 rows per round

    // fragment reads: global chunk c of row lives at LDS chunk c ^ (row&7)
    const int fl = lane & 15;
    const int g = lane >> 4;
    const int s7 = fl & 7;
    const int swz0 = (g ^ s7) * 8;          // ks = 0 chunk
    const int swz1 = ((g + 4) ^ s7) * 8;    // ks = 32 chunk
    int aoff[4], boff[4];
    #pragma unroll
    for (int i = 0; i < 4; ++i) {
        aoff[i] = (wm + i * 16 + fl) * BK;
        boff[i] = (wn + i * 16 + fl) * BK;
    }

    floatx4 acc[4][4];
    #pragma unroll
    for (int i = 0; i < 4; ++i)
        #pragma unroll
        for (int j = 0; j < 4; ++j) {
            acc[i][j][0] = 0.f; acc[i][j][1] = 0.f;
            acc[i][j][2] = 0.f; acc[i][j][3] = 0.f;
        }

    const int NT = K / BK;

    // preload tile 0 into buffer 0 (8 loads)
    #pragma unroll
    for (int r = 0; r < 4; ++r) {
        async_cp16(Ag + r * gstep, &As[0][t * 8 + r * 2048]);
        async_cp16(Bg + r * gstep, &Bs[0][t * 8 + r * 2048]);
    }

    for (int it = 0; it < NT; ++it) {
        const int cur = it & 1;
        if (it + 1 < NT) {
            const int nxt = cur ^ 1;
            const size_t koff = (size_t)(it + 1) * BK;
            #pragma unroll
            for (int r = 0; r < 4; ++r) {
                async_cp16(Ag + koff + r * gstep, &As[nxt][t * 8 + r * 2048]);
                async_cp16(Bg + koff + r * gstep, &Bs[nxt][t * 8 + r * 2048]);
            }
            // wait only the PREVIOUS tile's 8 loads (the 8 just issued stay in flight)
            asm volatile("s_waitcnt vmcnt(8)" ::: "memory");
        } else {
            asm volatile("s_waitcnt vmcnt(0)" ::: "memory");
        }
        asm volatile("s_barrier" ::: "memory");   // all waves' tile-it loads landed

        #pragma unroll
        for (int ks = 0; ks < 2; ++ks) {
            const int sw = ks ? swz1 : swz0;
            short8 af[4], bfr[4];
            #pragma unroll
            for (int i = 0; i < 4; ++i) af[i] = *(const short8*)&As[cur][aoff[i] + sw];
            #pragma unroll
            for (int j = 0; j < 4; ++j) bfr[j] = *(const short8*)&Bs[cur][boff[j] + sw];
            #pragma unroll
            for (int i = 0; i < 4; ++i)
                #pragma unroll
                for (int j = 0; j < 4; ++j)
                    acc[i][j] = __builtin_amdgcn_mfma_f32_16x16x32_bf16(af[i], bfr[j], acc[i][j], 0, 0, 0);
        }
        if (it + 1 < NT)
            asm volatile("s_barrier" ::: "memory"); // reads of buf[cur] done before it's re-staged
    }

    const int r0 = (lane >> 4) * 4;
    #pragma unroll
    for (int j = 0; j < 4; ++j) {
        const int gcol = bn * 128 + wn + j * 16 + fl;
        float bval = 0.f;
        if (EPI != EPI_NONE) bval = bf2f(bias[gcol]);
        #pragma unroll
        for (int i = 0; i < 4; ++i) {
            const int growb = bm * 128 + wm + i * 16 + r0;
            #pragma unroll
            for (int r = 0; r < 4; ++r) {
                const size_t idx = (size_t)(growb + r) * N + gcol;
                float v = acc[i][j][r];
                if (EPI == EPI_NONE) {
                    C[idx] = f2bf(v);
                } else if (EPI == EPI_BIAS_RELU) {
                    v += bval;
                    v = v > 0.f ? v : 0.f;
                    C[idx] = f2bf(v);
                } else {
                    float nh = hf[idx] + v + bval;
                    hf[idx] = nh;
                    hb[idx] = f2bf(nh);
                }
            }
        }
    }
}

// MFMA flash attention (validated round 4). blockIdx = pair*4 + qquarter.
__global__ __launch_bounds__(128) void attn_mfma(
    const unsigned short* __restrict__ Q,
    const unsigned short* __restrict__ Kx,
    const unsigned short* __restrict__ Vx,
    const float* __restrict__ maskf,
    unsigned short* __restrict__ Out)
{
    __shared__ __align__(16) unsigned short Vt[16 * 520];
    __shared__ __align__(16) unsigned short Pb[2][64 * 40];
    __shared__ float Ms[512];
    __shared__ float cnt_s;

    const int t = threadIdx.x;
    const int lane = t & 63;
    const int wave = t >> 6;
    const int p = blockIdx.x >> 2;
    const int qq = blockIdx.x & 3;
    const int b2 = p & 31;
    const int h2 = p >> 5;
    const int fm = lane & 15;
    const int g = lane >> 4;

    const unsigned short* Qg = Q + (size_t)p * 8192;
    const unsigned short* Kg = Kx + (size_t)p * 8192;
    const unsigned short* Vg = Vx + (size_t)p * 8192;

    #pragma unroll
    for (int rr = 0; rr < 4; ++rr) {
        const int row = t * 4 + rr;
        short8 v0 = *(const short8*)&Vg[row * 16];
        short8 v1 = *(const short8*)&Vg[row * 16 + 8];
        #pragma unroll
        for (int d = 0; d < 8; ++d) Vt[d * 520 + row] = (unsigned short)v0[d];
        #pragma unroll
        for (int d = 0; d < 8; ++d) Vt[(d + 8) * 520 + row] = (unsigned short)v1[d];
    }
    if (t == 0) cnt_s = 0.f;
    __syncthreads();
    float pc = 0.f;
    #pragma unroll
    for (int it = 0; it < 4; ++it) {
        int i = it * 128 + t;
        float mv = maskf[b2 * 512 + i];
        Ms[i] = mv; pc += mv;
    }
    atomicAdd(&cnt_s, pc);
    __syncthreads();
    const float cnt = cnt_s;

    const int qbase = qq * 128 + wave * 64;
    short8 qf[4];
    #pragma unroll
    for (int i = 0; i < 4; ++i) {
        short8 z = {0,0,0,0,0,0,0,0};
        if (g < 2) z = *(const short8*)&Qg[(qbase + i * 16 + fm) * 16 + g * 8];
        qf[i] = z;
    }

    float m_[4][4], l_[4][4];
    floatx4 O[4];
    #pragma unroll
    for (int i = 0; i < 4; ++i) {
        #pragma unroll
        for (int r = 0; r < 4; ++r) { m_[i][r] = -1e30f; l_[i][r] = 0.f; }
        O[i][0] = 0.f; O[i][1] = 0.f; O[i][2] = 0.f; O[i][3] = 0.f;
    }

    unsigned short* Pw = &Pb[wave][0];

    for (int kb = 0; kb < 512; kb += 32) {
        short8 kf0 = {0,0,0,0,0,0,0,0}, kf1 = {0,0,0,0,0,0,0,0};
        if (g < 2) {
            kf0 = *(const short8*)&Kg[(kb + fm) * 16 + g * 8];
            kf1 = *(const short8*)&Kg[(kb + 16 + fm) * 16 + g * 8];
        }
        const float msk0 = Ms[kb + fm];
        const float msk1 = Ms[kb + 16 + fm];

        floatx4 zero4 = {0.f, 0.f, 0.f, 0.f};
        floatx4 s0[4], s1[4];
        #pragma unroll
        for (int i = 0; i < 4; ++i) {
            s0[i] = __builtin_amdgcn_mfma_f32_16x16x32_bf16(qf[i], kf0, zero4, 0, 0, 0);
            s1[i] = __builtin_amdgcn_mfma_f32_16x16x32_bf16(qf[i], kf1, zero4, 0, 0, 0);
        }

        #pragma unroll
        for (int i = 0; i < 4; ++i) {
            #pragma unroll
            for (int r = 0; r < 4; ++r) {
                float a0 = (msk0 != 0.f) ? -1e30f : s0[i][r] * NORM_;
                float a1 = (msk1 != 0.f) ? -1e30f : s1[i][r] * NORM_;
                float mx = fmaxf(a0, a1);
                mx = fmaxf(mx, __shfl_xor(mx, 1));
                mx = fmaxf(mx, __shfl_xor(mx, 2));
                mx = fmaxf(mx, __shfl_xor(mx, 4));
                mx = fmaxf(mx, __shfl_xor(mx, 8));
                const float mo = m_[i][r];
                const float mn = fmaxf(mo, mx);
                const float alpha = __expf(mo - mn);
                float w0 = (msk0 != 0.f) ? 0.f : __expf(a0 - mn);
                float w1 = (msk1 != 0.f) ? 0.f : __expf(a1 - mn);
                float rs = w0 + w1;
                rs += __shfl_xor(rs, 1);
                rs += __shfl_xor(rs, 2);
                rs += __shfl_xor(rs, 4);
                rs += __shfl_xor(rs, 8);
                l_[i][r] = l_[i][r] * alpha + rs;
                m_[i][r] = mn;
                O[i][r] *= alpha;
                const int qloc = i * 16 + g * 4 + r;
                Pw[qloc * 40 + fm] = f2bf(w0);
                Pw[qloc * 40 + 16 + fm] = f2bf(w1);
            }
        }
        asm volatile("s_waitcnt lgkmcnt(0)" ::: "memory");

        short8 vtf = *(const short8*)&Vt[fm * 520 + kb + g * 8];
        #pragma unroll
        for (int i = 0; i < 4; ++i) {
            short8 pf = *(const short8*)&Pw[(i * 16 + fm) * 40 + g * 8];
            O[i] = __builtin_amdgcn_mfma_f32_16x16x32_bf16(pf, vtf, O[i], 0, 0, 0);
        }
    }

    #pragma unroll
    for (int i = 0; i < 4; ++i) {
        #pragma unroll
        for (int r = 0; r < 4; ++r) {
            const float M = fmaxf(m_[i][r], -30.f);
            const float adj = __expf(m_[i][r] - M);
            const float lf = l_[i][r] * adj + cnt * __expf(-30.f - M);
            const float oval = O[i][r] * adj / lf;
            const int n = qbase + i * 16 + g * 4 + r;
            Out[((size_t)(b2 * 512 + n)) * 128 + h2 * 16 + fm] = f2bf(oval);
        }
    }
}

__global__ __launch_bounds__(256) void write_h(const float* __restrict__ hf,
                                               void* __restrict__ out,
                                               const int* __restrict__ flag)
{
    const size_t i = ((size_t)blockIdx.x * 256 + threadIdx.x) * 4;
    floatx4 v = *(const floatx4*)&hf[i];
    if (*flag) {
        *(floatx4*)((float*)out + i) = v;
    } else {
        unsigned int p0 = (unsigned int)f2bf(v[0]) | ((unsigned int)f2bf(v[1]) << 16);
        unsigned int p1 = (unsigned int)f2bf(v[2]) | ((unsigned int)f2bf(v[3]) << 16);
        unsigned int* o = (unsigned int*)((unsigned short*)out + i);
        o[0] = p0; o[1] = p1;
    }
}

__global__ __launch_bounds__(256) void mean_kernel(const float* __restrict__ hf,
                                                   void* __restrict__ out,
                                                   const int* __restrict__ flag)
{
    const int b = blockIdx.x >> 2;
    const int e = ((blockIdx.x & 3) * 256) + threadIdx.x;
    float s = 0.f;
    for (int n = 0; n < 512; ++n) s += hf[((size_t)(b * 512 + n)) * 1024 + e];
    s *= (1.0f / 512.0f);
    const size_t off = (size_t)16384 * 1024 + b * 1024 + e;
    if (*flag) ((float*)out)[off] = s;
    else       ((unsigned short*)out)[off] = f2bf(s);
}

extern "C" void kernel_launch(void* const* d_in, const int* in_sizes, int n_in,
                              void* d_out, int out_size, void* d_ws, size_t ws_size,
                              hipStream_t stream)
{
    const void* x  = d_in[0];
    const unsigned int* mask = (const unsigned int*)d_in[1];

    char* ws = (char*)d_ws;
    float* hf = (float*)ws;                     ws += (size_t)16384 * 1024 * 4;   // 64 MB
    unsigned short* hb = (unsigned short*)ws;   ws += (size_t)16384 * 1024 * 2;   // 32 MB
    char* shared_rg = ws;                       ws += (size_t)16384 * 2048 * 2;   // 64 MB
    unsigned short* act = (unsigned short*)shared_rg;
    unsigned short* q  = (unsigned short*)shared_rg;
    unsigned short* k  = q + (size_t)16384 * 128;
    unsigned short* v  = k + (size_t)16384 * 128;
    unsigned short* ao = v + (size_t)16384 * 128;
    unsigned short* cWq = (unsigned short*)ws;  ws += (size_t)393216 * 2;
    unsigned short* cWk = (unsigned short*)ws;  ws += (size_t)393216 * 2;
    unsigned short* cWv = (unsigned short*)ws;  ws += (size_t)393216 * 2;
    unsigned short* cWo = (unsigned short*)ws;  ws += (size_t)393216 * 2;
    unsigned short* cbo = (unsigned short*)ws;  ws += (size_t)3072 * 2;
    unsigned short* cW1 = (unsigned short*)ws;  ws += (size_t)6291456 * 2;
    unsigned short* cb1 = (unsigned short*)ws;  ws += (size_t)6144 * 2;
    unsigned short* cW2 = (unsigned short*)ws;  ws += (size_t)6291456 * 2;
    unsigned short* cb2 = (unsigned short*)ws;  ws += (size_t)3072 * 2;
    float* maskf = (float*)ws;                  ws += (size_t)16384 * 4;
    int* flag = (int*)ws;                       ws += 256;

    detect_dtype<<<1, 256, 0, stream>>>((const unsigned int*)x, flag);

    auto conv = [&](const void* s, unsigned short* d, int n) {
        conv_to_bf16<<<(n / 8 + 255) / 256, 256, 0, stream>>>(s, d, n, flag);
    };
    conv(d_in[2], cWq, 393216);
    conv(d_in[3], cWk, 393216);
    conv(d_in[4], cWv, 393216);
    conv(d_in[5], cWo, 393216);
    conv(d_in[6], cbo, 3072);
    conv(d_in[7], cW1, 6291456);
    conv(d_in[8], cb1, 6144);
    conv(d_in[9], cW2, 6291456);
    conv(d_in[10], cb2, 3072);

    mask_expand<<<64, 256, 0, stream>>>(mask, maskf);
    init_h<<<8192, 256, 0, stream>>>(x, hf, hb, flag);

    for (int l = 0; l < 3; ++l) {
        const unsigned short* wq  = cWq + (size_t)l * 131072;
        const unsigned short* wk  = cWk + (size_t)l * 131072;
        const unsigned short* wv  = cWv + (size_t)l * 131072;
        const unsigned short* wo  = cWo + (size_t)l * 131072;
        const unsigned short* bol = cbo + (size_t)l * 1024;
        const unsigned short* w1  = cW1 + (size_t)l * 2097152;
        const unsigned short* b1l = cb1 + (size_t)l * 2048;
        const unsigned short* w2  = cW2 + (size_t)l * 2097152;
        const unsigned short* b2l = cb2 + (size_t)l * 1024;

        // grid: x = bm (fastest -> B-slab L2 reuse), y = bn
        gemm_bt<EPI_NONE><<<dim3(128, 1, 3), 256, 0, stream>>>(
            hb, wq, wk, wv, q, k, v, nullptr, nullptr, nullptr, 128, 1024);
        attn_mfma<<<1024, 128, 0, stream>>>(q, k, v, maskf, ao);
        gemm_bt<EPI_BIAS_RES><<<dim3(128, 8, 1), 256, 0, stream>>>(
            ao, wo, wo, wo, nullptr, nullptr, nullptr, bol, hf, hb, 1024, 128);
        gemm_bt<EPI_BIAS_RELU><<<dim3(128, 16, 1), 256, 0, stream>>>(
            hb, w1, w1, w1, act, act, act, b1l, nullptr, nullptr, 2048, 1024);
        gemm_bt<EPI_BIAS_RES><<<dim3(128, 8, 1), 256, 0, stream>>>(
            act, w2, w2, w2, nullptr, nullptr, nullptr, b2l, hf, hb, 1024, 2048);
    }

    write_h<<<16384, 256, 0, stream>>>(hf, d_out, flag);
    mean_kernel<<<128, 256, 0, stream>>>(hf, d_out, flag);
}